// Round 1
// baseline (2271.896 us; speedup 1.0000x reference)
//
#include <hip/hip_runtime.h>

#define TB 256
#define BM 64
#define BK 32
#define BN 128
#define ASTR 68   // BM + 4, keeps ds_read_b128 of A at <=2-way bank conflict

static constexpr int NN = 20000;
static constexpr int NE = 320000;

// workspace layout (floats)
static constexpr long long OFF_HN   = 0;          // N*128
static constexpr long long OFF_OW   = 2560000;    // E*128
static constexpr long long OFF_S    = 43520000;   // E      (s, then e after k4)
static constexpr long long OFF_M    = 43840000;   // N      (flipped-uint max)
static constexpr long long OFF_DEN  = 43860000;   // N
static constexpr long long OFF_HAGG = 43880000;   // N*256
static constexpr long long WS_FLOATS = 49000000;  // 196 MB

// d_out layout (floats): h_out, w_out, sat
static constexpr long long OUT_HOUT = 0;
static constexpr long long OUT_WOUT = 2560000;    // also used as w2 scratch
static constexpr long long OUT_SAT  = 43520000;

__device__ __forceinline__ float lrelu(float x){ return x >= 0.f ? x : 0.1f*x; }

// monotone float<->uint mapping for atomicMax on floats
__device__ __forceinline__ unsigned flipf(float f){
    unsigned u = __float_as_uint(f);
    return (u & 0x80000000u) ? ~u : (u | 0x80000000u);
}
__device__ __forceinline__ float unflipf(unsigned u){
    return __uint_as_float((u & 0x80000000u) ? (u & 0x7fffffffu) : ~u);
}

__device__ __forceinline__ void store_At(float (*Ast)[ASTR], int k4, int r, float4 v){
    Ast[k4+0][r] = v.x; Ast[k4+1][r] = v.y; Ast[k4+2][r] = v.z; Ast[k4+3][r] = v.w;
}

// per-thread 4x8 tile: rows r0..r0+3, cols {c0..c0+3} u {64+c0..64+c0+3}
__device__ __forceinline__ void mm_chunk(const float (*Ast)[ASTR], const float (*Bs)[BN],
                                         int r0, int c0, float acc[4][8]){
#pragma unroll 4
    for (int k = 0; k < BK; ++k){
        const float4 av = *(const float4*)&Ast[k][r0];
        const float4 b0 = *(const float4*)&Bs[k][c0];
        const float4 b1 = *(const float4*)&Bs[k][64 + c0];
        const float a0=av.x, a1=av.y, a2=av.z, a3=av.w;
        const float b[8] = {b0.x,b0.y,b0.z,b0.w,b1.x,b1.y,b1.z,b1.w};
#pragma unroll
        for (int j = 0; j < 8; ++j){
            acc[0][j] = fmaf(a0, b[j], acc[0][j]);
            acc[1][j] = fmaf(a1, b[j], acc[1][j]);
            acc[2][j] = fmaf(a2, b[j], acc[2][j]);
            acc[3][j] = fmaf(a3, b[j], acc[3][j]);
        }
    }
}

__device__ __forceinline__ void load_B(const float* __restrict__ W, int kc,
                                       float (*Bs)[BN], int tid){
#pragma unroll
    for (int p = 0; p < 4; ++p){
        int idx = p*TB + tid;
        int row = idx >> 5;
        int c4  = (idx & 31) << 2;
        *(float4*)&Bs[row][c4] = *(const float4*)&W[(size_t)(kc+row)*BN + c4];
    }
}

// ---------------- k0: init atomic buffers ----------------
__global__ __launch_bounds__(TB) void k0_init(float* __restrict__ hagg,
                                              float* __restrict__ den,
                                              unsigned* __restrict__ m_u){
    int i = blockIdx.x*TB + threadIdx.x;   // grid covers N*256
    hagg[i] = 0.f;
    if (i < NN){ den[i] = 0.f; m_u[i] = 0u; }
}

// ---------------- k1: hn = h @ W_node ----------------
__global__ __launch_bounds__(TB) void k1_hn(const float* __restrict__ h,
                                            const float* __restrict__ Wn,
                                            float* __restrict__ hn){
    __shared__ float Ast[BK][ASTR];
    __shared__ float Bs[BK][BN];
    const int tid = threadIdx.x;
    const int rbase = blockIdx.x * BM;
    const int tc = tid & 15, tr = tid >> 4;
    const int r0 = tr*4, c0 = tc*4;
    float acc[4][8] = {};
    for (int kc = 0; kc < 128; kc += BK){
        __syncthreads();
        {
            int lr = tid >> 3, k4 = (tid & 7) << 2;
#pragma unroll
            for (int p = 0; p < 2; ++p){
                int r = p*32 + lr;
                int rr = rbase + r; if (rr >= NN) rr = NN-1;
                float4 v = *(const float4*)&h[(size_t)rr*128 + kc + k4];
                store_At(Ast, k4, r, v);
            }
        }
        load_B(Wn, kc, Bs, tid);
        __syncthreads();
        mm_chunk(Ast, Bs, r0, c0, acc);
    }
#pragma unroll
    for (int i = 0; i < 4; ++i){
        int rr = rbase + r0 + i;
        if (rr < NN){
            float4 o0 = {acc[i][0],acc[i][1],acc[i][2],acc[i][3]};
            float4 o1 = {acc[i][4],acc[i][5],acc[i][6],acc[i][7]};
            *(float4*)&hn[(size_t)rr*128 + c0] = o0;
            *(float4*)&hn[(size_t)rr*128 + 64 + c0] = o1;
        }
    }
}

// ---------------- k2: ow = edge_w @ W_eedge ; w1 = (lrelu(ow)@W_esf)*ow ----------------
__global__ __launch_bounds__(TB) void k2_ow(const float* __restrict__ ew,
                                            const float* __restrict__ We,
                                            const float* __restrict__ Wesf,
                                            float* __restrict__ ow,
                                            float* __restrict__ out_sat){
    __shared__ float Ast[BK][ASTR];
    __shared__ float Bs[BK][BN];
    __shared__ float sEsf[BN];
    const int tid = threadIdx.x;
    const int rbase = blockIdx.x * BM;
    const int tc = tid & 15, tr = tid >> 4;
    const int r0 = tr*4, c0 = tc*4;
    if (tid < BN) sEsf[tid] = Wesf[tid];
    float acc[4][8] = {};
    for (int kc = 0; kc < 128; kc += BK){
        __syncthreads();
        {
            int lr = tid >> 3, k4 = (tid & 7) << 2;
#pragma unroll
            for (int p = 0; p < 2; ++p){
                int r = p*32 + lr;
                float4 v = *(const float4*)&ew[(size_t)(rbase+r)*128 + kc + k4];
                store_At(Ast, k4, r, v);
            }
        }
        load_B(We, kc, Bs, tid);
        __syncthreads();
        mm_chunk(Ast, Bs, r0, c0, acc);
    }
#pragma unroll
    for (int i = 0; i < 4; ++i){
        float p = 0.f;
#pragma unroll
        for (int j = 0; j < 8; ++j){
            int col = (j < 4) ? (c0 + j) : (60 + c0 + j);
            p += lrelu(acc[i][j]) * sEsf[col];
        }
#pragma unroll
        for (int m = 1; m < 16; m <<= 1) p += __shfl_xor(p, m);
        int rr = rbase + r0 + i;
        float4 o0 = {acc[i][0],acc[i][1],acc[i][2],acc[i][3]};
        float4 o1 = {acc[i][4],acc[i][5],acc[i][6],acc[i][7]};
        *(float4*)&ow[(size_t)rr*128 + c0] = o0;
        *(float4*)&ow[(size_t)rr*128 + 64 + c0] = o1;
        float4 w10 = {p*o0.x, p*o0.y, p*o0.z, p*o0.w};
        float4 w11 = {p*o1.x, p*o1.y, p*o1.z, p*o1.w};
        *(float4*)&out_sat[(size_t)rr*384 + 256 + c0] = w10;
        *(float4*)&out_sat[(size_t)rr*384 + 256 + 64 + c0] = w11;
    }
}

// ---------------- k3: sat build + inw GEMM + attn dot + w2 + segment-max ----------------
__global__ __launch_bounds__(TB) void k3_fuse(const float* __restrict__ hn,
                                              const float* __restrict__ Wf,
                                              const float* __restrict__ bf,
                                              const float* __restrict__ Wattn,
                                              const int* __restrict__ src,
                                              const int* __restrict__ dst,
                                              float* __restrict__ out_sat,
                                              float* __restrict__ w2,
                                              float* __restrict__ s_ws,
                                              unsigned* __restrict__ m_u){
    __shared__ float Ast[BK][ASTR];
    __shared__ float Bs[BK][BN];
    __shared__ float sBf[BN], sAttn[BN];
    __shared__ int sSrc[BM], sDst[BM];
    const int tid = threadIdx.x;
    const int rbase = blockIdx.x * BM;
    const int tc = tid & 15, tr = tid >> 4;
    const int r0 = tr*4, c0 = tc*4;
    if (tid < BN){ sBf[tid] = bf[tid]; sAttn[tid] = Wattn[tid]; }
    if (tid < BM){ sSrc[tid] = src[rbase+tid]; sDst[tid] = dst[rbase+tid]; }
    float acc[4][8] = {};
    for (int chunk = 0; chunk < 12; ++chunk){
        int kc = chunk * BK;
        __syncthreads();
        {
            int lr = tid >> 3, k4 = (tid & 7) << 2;
#pragma unroll
            for (int p = 0; p < 2; ++p){
                int r = p*32 + lr;
                int rr = rbase + r;
                float4 v;
                if (chunk < 4){
                    v = *(const float4*)&hn[(size_t)sSrc[r]*128 + kc + k4];
                    *(float4*)&out_sat[(size_t)rr*384 + kc + k4] = v;
                } else if (chunk < 8){
                    v = *(const float4*)&hn[(size_t)sDst[r]*128 + (kc-128) + k4];
                    *(float4*)&out_sat[(size_t)rr*384 + kc + k4] = v;
                } else {
                    v = *(const float4*)&out_sat[(size_t)rr*384 + kc + k4]; // w1 (from k2)
                }
                store_At(Ast, k4, r, v);
            }
        }
        load_B(Wf, kc, Bs, tid);
        __syncthreads();
        mm_chunk(Ast, Bs, r0, c0, acc);
    }
#pragma unroll
    for (int i = 0; i < 4; ++i){
        float p = 0.f;
#pragma unroll
        for (int j = 0; j < 8; ++j){
            int col = (j < 4) ? (c0 + j) : (60 + c0 + j);
            float v = lrelu(acc[i][j] + sBf[col]);
            p += v * sAttn[col];
        }
#pragma unroll
        for (int m = 1; m < 16; m <<= 1) p += __shfl_xor(p, m);
        int rr = rbase + r0 + i;
        float4 w1a = *(const float4*)&out_sat[(size_t)rr*384 + 256 + c0];
        float4 w1b = *(const float4*)&out_sat[(size_t)rr*384 + 256 + 64 + c0];
        float4 w2a = {p*w1a.x, p*w1a.y, p*w1a.z, p*w1a.w};
        float4 w2b = {p*w1b.x, p*w1b.y, p*w1b.z, p*w1b.w};
        *(float4*)&w2[(size_t)rr*128 + c0] = w2a;
        *(float4*)&w2[(size_t)rr*128 + 64 + c0] = w2b;
        if (tc == 0){
            s_ws[rr] = p;
            atomicMax(&m_u[sDst[r0+i]], flipf(p));
        }
    }
}

// ---------------- k4: e = exp(s - m[dst]); denom += e ----------------
__global__ __launch_bounds__(TB) void k4_exp(float* __restrict__ s,
                                             const int* __restrict__ dst,
                                             const unsigned* __restrict__ m_u,
                                             float* __restrict__ den){
    int e = blockIdx.x*TB + threadIdx.x;
    float sv = s[e];
    int d = dst[e];
    float ev = expf(sv - unflipf(m_u[d]));
    s[e] = ev;
    atomicAdd(&den[d], ev);
}

// ---------------- k5: h_agg[dst] += alpha * [hs, w2]  (1 wave per edge) ----------------
__global__ __launch_bounds__(TB) void k5_hagg(const float* __restrict__ eV,
                                              const float* __restrict__ den,
                                              const float* __restrict__ hn,
                                              const float* __restrict__ w2,
                                              const int* __restrict__ src,
                                              const int* __restrict__ dst,
                                              float* __restrict__ hagg){
    int e = blockIdx.x*4 + (threadIdx.x >> 6);
    int lane = threadIdx.x & 63;
    int sI = src[e], dI = dst[e];
    float alpha = eV[e] / den[dI];
    int c = lane << 2;
    float4 v;
    if (c < 128) v = *(const float4*)&hn[(size_t)sI*128 + c];
    else         v = *(const float4*)&w2[(size_t)e*128 + (c-128)];
    float* dp = &hagg[(size_t)dI*256 + c];
    atomicAdd(dp+0, alpha*v.x);
    atomicAdd(dp+1, alpha*v.y);
    atomicAdd(dp+2, alpha*v.z);
    atomicAdd(dp+3, alpha*v.w);
}

// ---------------- k6: h_new = [h_agg, hn] @ W_conc + b_conc ; indeg select ----------------
__global__ __launch_bounds__(TB) void k6_conc(const float* __restrict__ hagg,
                                              const float* __restrict__ hn,
                                              const float* __restrict__ Wc,
                                              const float* __restrict__ bc,
                                              const float* __restrict__ den,
                                              float* __restrict__ hout){
    __shared__ float Ast[BK][ASTR];
    __shared__ float Bs[BK][BN];
    __shared__ float sBc[BN];
    const int tid = threadIdx.x;
    const int rbase = blockIdx.x * BM;
    const int tc = tid & 15, tr = tid >> 4;
    const int r0 = tr*4, c0 = tc*4;
    if (tid < BN) sBc[tid] = bc[tid];
    float acc[4][8] = {};
    for (int chunk = 0; chunk < 12; ++chunk){
        int kc = chunk * BK;
        __syncthreads();
        {
            int lr = tid >> 3, k4 = (tid & 7) << 2;
#pragma unroll
            for (int p = 0; p < 2; ++p){
                int r = p*32 + lr;
                int rr = rbase + r; if (rr >= NN) rr = NN-1;
                float4 v;
                if (chunk < 8) v = *(const float4*)&hagg[(size_t)rr*256 + kc + k4];
                else           v = *(const float4*)&hn[(size_t)rr*128 + (kc-256) + k4];
                store_At(Ast, k4, r, v);
            }
        }
        load_B(Wc, kc, Bs, tid);
        __syncthreads();
        mm_chunk(Ast, Bs, r0, c0, acc);
    }
#pragma unroll
    for (int i = 0; i < 4; ++i){
        int rr = rbase + r0 + i;
        if (rr >= NN) continue;
        bool keep = den[rr] > 0.f;
        float4 h0 = *(const float4*)&hn[(size_t)rr*128 + c0];
        float4 h1 = *(const float4*)&hn[(size_t)rr*128 + 64 + c0];
        float4 o0, o1;
        o0.x = keep ? acc[i][0] + sBc[c0+0] : h0.x;
        o0.y = keep ? acc[i][1] + sBc[c0+1] : h0.y;
        o0.z = keep ? acc[i][2] + sBc[c0+2] : h0.z;
        o0.w = keep ? acc[i][3] + sBc[c0+3] : h0.w;
        o1.x = keep ? acc[i][4] + sBc[64+c0+0] : h1.x;
        o1.y = keep ? acc[i][5] + sBc[64+c0+1] : h1.y;
        o1.z = keep ? acc[i][6] + sBc[64+c0+2] : h1.z;
        o1.w = keep ? acc[i][7] + sBc[64+c0+3] : h1.w;
        *(float4*)&hout[(size_t)rr*128 + c0] = o0;
        *(float4*)&hout[(size_t)rr*128 + 64 + c0] = o1;
    }
}

// ---------------- k7: w_out = [h_out[src], h_out[dst], w_bn, ow] @ W_aggre ----------------
__global__ __launch_bounds__(TB) void k7_out(const float* __restrict__ hout,
                                             const float* __restrict__ ow,
                                             const float* __restrict__ gamma,
                                             const float* __restrict__ beta,
                                             const float* __restrict__ Wa,
                                             const int* __restrict__ src,
                                             const int* __restrict__ dst,
                                             float* __restrict__ w2out){
    __shared__ float Ast[BK][ASTR];
    __shared__ float Bs[BK][BN];
    __shared__ int sSrc[BM], sDst[BM];
    const int tid = threadIdx.x;
    const int rbase = blockIdx.x * BM;
    const int tc = tid & 15, tr = tid >> 4;
    const int r0 = tr*4, c0 = tc*4;
    const float ISR = 0.9999950000374997f;  // 1/sqrt(1+1e-5)
    if (tid < BM){ sSrc[tid] = src[rbase+tid]; sDst[tid] = dst[rbase+tid]; }
    float acc[4][8] = {};
    for (int chunk = 0; chunk < 16; ++chunk){
        int kc = chunk * BK;
        __syncthreads();
        {
            int lr = tid >> 3, k4 = (tid & 7) << 2;
#pragma unroll
            for (int p = 0; p < 2; ++p){
                int r = p*32 + lr;
                int rr = rbase + r;
                float4 v;
                if (chunk < 4){
                    v = *(const float4*)&hout[(size_t)sSrc[r]*128 + kc + k4];
                } else if (chunk < 8){
                    v = *(const float4*)&hout[(size_t)sDst[r]*128 + (kc-128) + k4];
                } else if (chunk < 12){
                    int cb = (kc - 256) + k4;
                    float4 g = *(const float4*)&gamma[cb];
                    float4 b = *(const float4*)&beta[cb];
                    v = *(const float4*)&w2out[(size_t)rr*128 + cb];
                    v.x = v.x*ISR*g.x + b.x;
                    v.y = v.y*ISR*g.y + b.y;
                    v.z = v.z*ISR*g.z + b.z;
                    v.w = v.w*ISR*g.w + b.w;
                } else {
                    v = *(const float4*)&ow[(size_t)rr*128 + (kc-384) + k4];
                }
                store_At(Ast, k4, r, v);
            }
        }
        load_B(Wa, kc, Bs, tid);
        __syncthreads();
        mm_chunk(Ast, Bs, r0, c0, acc);
    }
#pragma unroll
    for (int i = 0; i < 4; ++i){
        int rr = rbase + r0 + i;
        float4 o0 = {acc[i][0],acc[i][1],acc[i][2],acc[i][3]};
        float4 o1 = {acc[i][4],acc[i][5],acc[i][6],acc[i][7]};
        *(float4*)&w2out[(size_t)rr*128 + c0] = o0;
        *(float4*)&w2out[(size_t)rr*128 + 64 + c0] = o1;
    }
}

extern "C" void kernel_launch(void* const* d_in, const int* in_sizes, int n_in,
                              void* d_out, int out_size, void* d_ws, size_t ws_size,
                              hipStream_t stream){
    (void)in_sizes; (void)n_in; (void)out_size;
    const float* h       = (const float*)d_in[0];
    const float* edge_w  = (const float*)d_in[1];
    const float* W_node  = (const float*)d_in[2];
    const float* W_eedge = (const float*)d_in[3];
    const float* W_esf   = (const float*)d_in[4];
    const float* W_fuse  = (const float*)d_in[5];
    const float* b_fuse  = (const float*)d_in[6];
    const float* W_attn  = (const float*)d_in[7];
    const float* W_conc  = (const float*)d_in[8];
    const float* b_conc  = (const float*)d_in[9];
    const float* gamma   = (const float*)d_in[10];
    const float* beta    = (const float*)d_in[11];
    const float* W_aggre = (const float*)d_in[12];
    const int*   src     = (const int*)d_in[13];
    const int*   dst     = (const int*)d_in[14];

    float* out    = (float*)d_out;
    float* o_hout = out + OUT_HOUT;
    float* o_wout = out + OUT_WOUT;   // holds w2 until k7 overwrites with w_out
    float* o_sat  = out + OUT_SAT;

    if (ws_size < (size_t)WS_FLOATS * 4) return;  // fail loudly via validation
    float* ws     = (float*)d_ws;
    float* w_hn   = ws + OFF_HN;
    float* w_ow   = ws + OFF_OW;
    float* w_s    = ws + OFF_S;
    unsigned* w_m = (unsigned*)(ws + OFF_M);
    float* w_den  = ws + OFF_DEN;
    float* w_hagg = ws + OFF_HAGG;

    hipLaunchKernelGGL(k0_init, dim3(NN*256/TB), dim3(TB), 0, stream, w_hagg, w_den, w_m);
    hipLaunchKernelGGL(k1_hn,   dim3((NN+BM-1)/BM), dim3(TB), 0, stream, h, W_node, w_hn);
    hipLaunchKernelGGL(k2_ow,   dim3(NE/BM), dim3(TB), 0, stream, edge_w, W_eedge, W_esf, w_ow, o_sat);
    hipLaunchKernelGGL(k3_fuse, dim3(NE/BM), dim3(TB), 0, stream, w_hn, W_fuse, b_fuse, W_attn,
                       src, dst, o_sat, o_wout, w_s, w_m);
    hipLaunchKernelGGL(k4_exp,  dim3(NE/TB), dim3(TB), 0, stream, w_s, dst, w_m, w_den);
    hipLaunchKernelGGL(k5_hagg, dim3(NE/4), dim3(TB), 0, stream, w_s, w_den, w_hn, o_wout,
                       src, dst, w_hagg);
    hipLaunchKernelGGL(k6_conc, dim3((NN+BM-1)/BM), dim3(TB), 0, stream, w_hagg, w_hn,
                       W_conc, b_conc, w_den, o_hout);
    hipLaunchKernelGGL(k7_out,  dim3(NE/BM), dim3(TB), 0, stream, o_hout, w_ow, gamma, beta,
                       W_aggre, src, dst, o_wout);
}

// Round 2
// 1378.753 us; speedup vs baseline: 1.6478x; 1.6478x over previous
//
#include <hip/hip_runtime.h>

#define TB 256
#define BM 64
#define BK 32
#define BN 128
#define ASTR 68   // BM + 4, keeps ds_read_b128 of A at <=2-way bank conflict
#define MAXD 160  // per-node edge cache; P(deg>160) ~ 0 for E/N=16 multinomial

static constexpr int NN = 20000;
static constexpr int NE = 320000;

// workspace layout (floats)
static constexpr long long OFF_HN   = 0;          // N*128
static constexpr long long OFF_OW   = 2560000;    // E*128
static constexpr long long OFF_S    = 43520000;   // E  (raw attention scalar s)
static constexpr long long OFF_DEN  = 43840000;   // N  (softmax denom; 0 iff indeg==0)
static constexpr long long OFF_CUR  = 43860000;   // N ints (counts -> start offsets -> end offsets)
static constexpr long long OFF_HAGG = 43880000;   // N*256
static constexpr long long WS_FLOATS = 49000000;  // 196 MB (same as round-1 proven budget)

// d_out layout (floats): h_out, w_out, sat
static constexpr long long OUT_HOUT = 0;
static constexpr long long OUT_WOUT = 2560000;    // holds w2 until k7 overwrites with w_out
static constexpr long long OUT_SAT  = 43520000;
// h_out region (2.56M floats) doubles as pre-k6 scratch for eidx[E] + offs[N] (1.36 MB)

__device__ __forceinline__ float lrelu(float x){ return x >= 0.f ? x : 0.1f*x; }

__device__ __forceinline__ void store_At(float (*Ast)[ASTR], int k4, int r, float4 v){
    Ast[k4+0][r] = v.x; Ast[k4+1][r] = v.y; Ast[k4+2][r] = v.z; Ast[k4+3][r] = v.w;
}

// per-thread 4x8 tile: rows r0..r0+3, cols {c0..c0+3} u {64+c0..64+c0+3}
__device__ __forceinline__ void mm_chunk(const float (*Ast)[ASTR], const float (*Bs)[BN],
                                         int r0, int c0, float acc[4][8]){
#pragma unroll 4
    for (int k = 0; k < BK; ++k){
        const float4 av = *(const float4*)&Ast[k][r0];
        const float4 b0 = *(const float4*)&Bs[k][c0];
        const float4 b1 = *(const float4*)&Bs[k][64 + c0];
        const float a0=av.x, a1=av.y, a2=av.z, a3=av.w;
        const float b[8] = {b0.x,b0.y,b0.z,b0.w,b1.x,b1.y,b1.z,b1.w};
#pragma unroll
        for (int j = 0; j < 8; ++j){
            acc[0][j] = fmaf(a0, b[j], acc[0][j]);
            acc[1][j] = fmaf(a1, b[j], acc[1][j]);
            acc[2][j] = fmaf(a2, b[j], acc[2][j]);
            acc[3][j] = fmaf(a3, b[j], acc[3][j]);
        }
    }
}

__device__ __forceinline__ void load_B(const float* __restrict__ W, int kc,
                                       float (*Bs)[BN], int tid){
#pragma unroll
    for (int p = 0; p < 4; ++p){
        int idx = p*TB + tid;
        int row = idx >> 5;
        int c4  = (idx & 31) << 2;
        *(float4*)&Bs[row][c4] = *(const float4*)&W[(size_t)(kc+row)*BN + c4];
    }
}

// block-wide reductions (256 threads = 4 waves)
__device__ __forceinline__ float blockMax(float v, float* sh4){
#pragma unroll
    for (int m = 32; m; m >>= 1) v = fmaxf(v, __shfl_xor(v, m));
    if ((threadIdx.x & 63) == 0) sh4[threadIdx.x >> 6] = v;
    __syncthreads();
    float r = fmaxf(fmaxf(sh4[0], sh4[1]), fmaxf(sh4[2], sh4[3]));
    __syncthreads();
    return r;
}
__device__ __forceinline__ float blockSum(float v, float* sh4){
#pragma unroll
    for (int m = 32; m; m >>= 1) v += __shfl_xor(v, m);
    if ((threadIdx.x & 63) == 0) sh4[threadIdx.x >> 6] = v;
    __syncthreads();
    float r = sh4[0] + sh4[1] + sh4[2] + sh4[3];
    __syncthreads();
    return r;
}

// ---------------- sort pipeline: kA init, kB count, kC scan, kD scatter ----------------
__global__ __launch_bounds__(TB) void kA_init(int* __restrict__ cur){
    int i = blockIdx.x*TB + threadIdx.x;
    if (i < NN) cur[i] = 0;
}

__global__ __launch_bounds__(TB) void kB_count(const int* __restrict__ dst,
                                               int* __restrict__ cur){
    int e = blockIdx.x*TB + threadIdx.x;
    atomicAdd(&cur[dst[e]], 1);
}

// single block: counts (in cur) -> exclusive scan; offs[i]=start, cur[i]=start (mutated by kD)
__global__ __launch_bounds__(TB) void kC_scan(int* __restrict__ cur,
                                              int* __restrict__ offs){
    __shared__ int part[TB];
    __shared__ int spre[TB];
    const int tid = threadIdx.x;
    const int CH = (NN + TB - 1) / TB;  // 79
    const int base = tid * CH;
    int sum = 0;
    for (int i = 0; i < CH; ++i){ int idx = base + i; if (idx < NN) sum += cur[idx]; }
    part[tid] = sum;
    __syncthreads();
    if (tid == 0){ int r = 0; for (int i = 0; i < TB; ++i){ spre[i] = r; r += part[i]; } }
    __syncthreads();
    int run = spre[tid];
    for (int i = 0; i < CH; ++i){
        int idx = base + i;
        if (idx < NN){ int c = cur[idx]; offs[idx] = run; cur[idx] = run; run += c; }
    }
}

__global__ __launch_bounds__(TB) void kD_scatter(const int* __restrict__ dst,
                                                 int* __restrict__ cur,
                                                 int* __restrict__ eidx){
    int e = blockIdx.x*TB + threadIdx.x;
    int p = atomicAdd(&cur[dst[e]], 1);
    eidx[p] = e;
}

// ---------------- k1: hn = h @ W_node ----------------
__global__ __launch_bounds__(TB) void k1_hn(const float* __restrict__ h,
                                            const float* __restrict__ Wn,
                                            float* __restrict__ hn){
    __shared__ float Ast[BK][ASTR];
    __shared__ float Bs[BK][BN];
    const int tid = threadIdx.x;
    const int rbase = blockIdx.x * BM;
    const int tc = tid & 15, tr = tid >> 4;
    const int r0 = tr*4, c0 = tc*4;
    float acc[4][8] = {};
    for (int kc = 0; kc < 128; kc += BK){
        __syncthreads();
        {
            int lr = tid >> 3, k4 = (tid & 7) << 2;
#pragma unroll
            for (int p = 0; p < 2; ++p){
                int r = p*32 + lr;
                int rr = rbase + r; if (rr >= NN) rr = NN-1;
                float4 v = *(const float4*)&h[(size_t)rr*128 + kc + k4];
                store_At(Ast, k4, r, v);
            }
        }
        load_B(Wn, kc, Bs, tid);
        __syncthreads();
        mm_chunk(Ast, Bs, r0, c0, acc);
    }
#pragma unroll
    for (int i = 0; i < 4; ++i){
        int rr = rbase + r0 + i;
        if (rr < NN){
            float4 o0 = {acc[i][0],acc[i][1],acc[i][2],acc[i][3]};
            float4 o1 = {acc[i][4],acc[i][5],acc[i][6],acc[i][7]};
            *(float4*)&hn[(size_t)rr*128 + c0] = o0;
            *(float4*)&hn[(size_t)rr*128 + 64 + c0] = o1;
        }
    }
}

// ---------------- k2: ow = edge_w @ W_eedge ; w1 = (lrelu(ow)@W_esf)*ow ----------------
__global__ __launch_bounds__(TB) void k2_ow(const float* __restrict__ ew,
                                            const float* __restrict__ We,
                                            const float* __restrict__ Wesf,
                                            float* __restrict__ ow,
                                            float* __restrict__ out_sat){
    __shared__ float Ast[BK][ASTR];
    __shared__ float Bs[BK][BN];
    __shared__ float sEsf[BN];
    const int tid = threadIdx.x;
    const int rbase = blockIdx.x * BM;
    const int tc = tid & 15, tr = tid >> 4;
    const int r0 = tr*4, c0 = tc*4;
    if (tid < BN) sEsf[tid] = Wesf[tid];
    float acc[4][8] = {};
    for (int kc = 0; kc < 128; kc += BK){
        __syncthreads();
        {
            int lr = tid >> 3, k4 = (tid & 7) << 2;
#pragma unroll
            for (int p = 0; p < 2; ++p){
                int r = p*32 + lr;
                float4 v = *(const float4*)&ew[(size_t)(rbase+r)*128 + kc + k4];
                store_At(Ast, k4, r, v);
            }
        }
        load_B(We, kc, Bs, tid);
        __syncthreads();
        mm_chunk(Ast, Bs, r0, c0, acc);
    }
#pragma unroll
    for (int i = 0; i < 4; ++i){
        float p = 0.f;
#pragma unroll
        for (int j = 0; j < 8; ++j){
            int col = (j < 4) ? (c0 + j) : (60 + c0 + j);
            p += lrelu(acc[i][j]) * sEsf[col];
        }
#pragma unroll
        for (int m = 1; m < 16; m <<= 1) p += __shfl_xor(p, m);
        int rr = rbase + r0 + i;
        float4 o0 = {acc[i][0],acc[i][1],acc[i][2],acc[i][3]};
        float4 o1 = {acc[i][4],acc[i][5],acc[i][6],acc[i][7]};
        *(float4*)&ow[(size_t)rr*128 + c0] = o0;
        *(float4*)&ow[(size_t)rr*128 + 64 + c0] = o1;
        float4 w10 = {p*o0.x, p*o0.y, p*o0.z, p*o0.w};
        float4 w11 = {p*o1.x, p*o1.y, p*o1.z, p*o1.w};
        *(float4*)&out_sat[(size_t)rr*384 + 256 + c0] = w10;
        *(float4*)&out_sat[(size_t)rr*384 + 256 + 64 + c0] = w11;
    }
}

// ---------------- k3: sat build + inw GEMM + attn dot + w2 + s ----------------
__global__ __launch_bounds__(TB) void k3_fuse(const float* __restrict__ hn,
                                              const float* __restrict__ Wf,
                                              const float* __restrict__ bf,
                                              const float* __restrict__ Wattn,
                                              const int* __restrict__ src,
                                              const int* __restrict__ dst,
                                              float* __restrict__ out_sat,
                                              float* __restrict__ w2,
                                              float* __restrict__ s_ws){
    __shared__ float Ast[BK][ASTR];
    __shared__ float Bs[BK][BN];
    __shared__ float sBf[BN], sAttn[BN];
    __shared__ int sSrc[BM], sDst[BM];
    const int tid = threadIdx.x;
    const int rbase = blockIdx.x * BM;
    const int tc = tid & 15, tr = tid >> 4;
    const int r0 = tr*4, c0 = tc*4;
    if (tid < BN){ sBf[tid] = bf[tid]; sAttn[tid] = Wattn[tid]; }
    if (tid < BM){ sSrc[tid] = src[rbase+tid]; sDst[tid] = dst[rbase+tid]; }
    float acc[4][8] = {};
    for (int chunk = 0; chunk < 12; ++chunk){
        int kc = chunk * BK;
        __syncthreads();
        {
            int lr = tid >> 3, k4 = (tid & 7) << 2;
#pragma unroll
            for (int p = 0; p < 2; ++p){
                int r = p*32 + lr;
                int rr = rbase + r;
                float4 v;
                if (chunk < 4){
                    v = *(const float4*)&hn[(size_t)sSrc[r]*128 + kc + k4];
                    *(float4*)&out_sat[(size_t)rr*384 + kc + k4] = v;
                } else if (chunk < 8){
                    v = *(const float4*)&hn[(size_t)sDst[r]*128 + (kc-128) + k4];
                    *(float4*)&out_sat[(size_t)rr*384 + kc + k4] = v;
                } else {
                    v = *(const float4*)&out_sat[(size_t)rr*384 + kc + k4]; // w1 (from k2)
                }
                store_At(Ast, k4, r, v);
            }
        }
        load_B(Wf, kc, Bs, tid);
        __syncthreads();
        mm_chunk(Ast, Bs, r0, c0, acc);
    }
#pragma unroll
    for (int i = 0; i < 4; ++i){
        float p = 0.f;
#pragma unroll
        for (int j = 0; j < 8; ++j){
            int col = (j < 4) ? (c0 + j) : (60 + c0 + j);
            float v = lrelu(acc[i][j] + sBf[col]);
            p += v * sAttn[col];
        }
#pragma unroll
        for (int m = 1; m < 16; m <<= 1) p += __shfl_xor(p, m);
        int rr = rbase + r0 + i;
        float4 w1a = *(const float4*)&out_sat[(size_t)rr*384 + 256 + c0];
        float4 w1b = *(const float4*)&out_sat[(size_t)rr*384 + 256 + 64 + c0];
        float4 w2a = {p*w1a.x, p*w1a.y, p*w1a.z, p*w1a.w};
        float4 w2b = {p*w1b.x, p*w1b.y, p*w1b.z, p*w1b.w};
        *(float4*)&w2[(size_t)rr*128 + c0] = w2a;
        *(float4*)&w2[(size_t)rr*128 + 64 + c0] = w2b;
        if (tc == 0) s_ws[rr] = p;
    }
}

// ---------------- k5: per-node softmax + gather-aggregate (no atomics) ----------------
__global__ __launch_bounds__(TB) void k5_agg(const float* __restrict__ s,
                                             const float* __restrict__ hn,
                                             const float* __restrict__ w2,
                                             const int* __restrict__ src,
                                             const int* __restrict__ eidx,
                                             const int* __restrict__ offs,
                                             const int* __restrict__ cur,
                                             float* __restrict__ hagg,
                                             float* __restrict__ den){
    __shared__ int   sE[MAXD];
    __shared__ int   sSrc[MAXD];
    __shared__ float sA[MAXD];
    __shared__ float sh4[4];
    const int n = blockIdx.x, tid = threadIdx.x;
    const int start = offs[n];
    const int deg = cur[n] - start;   // cur[n] == end offset after kD
    // load edge ids, sort for deterministic accumulation order
    for (int i = tid; i < deg && i < MAXD; i += TB) sE[i] = eidx[start+i];
    __syncthreads();
    if (tid == 0 && deg > 1){
        int dd = deg < MAXD ? deg : MAXD;
        for (int i = 1; i < dd; ++i){
            int key = sE[i], j = i-1;
            while (j >= 0 && sE[j] > key){ sE[j+1] = sE[j]; --j; }
            sE[j+1] = key;
        }
    }
    __syncthreads();
    // segment max
    float lm = -3.402823466e38f;
    for (int i = tid; i < deg; i += TB){
        int e = (i < MAXD) ? sE[i] : eidx[start+i];
        lm = fmaxf(lm, s[e]);
    }
    const float m = blockMax(lm, sh4);
    // segment sum of exp
    float ls = 0.f;
    for (int i = tid; i < deg; i += TB){
        int e = (i < MAXD) ? sE[i] : eidx[start+i];
        ls += expf(s[e] - m);
    }
    const float denom = blockSum(ls, sh4);
    // cache alpha & src
    for (int i = tid; i < deg && i < MAXD; i += TB){
        int e = sE[i];
        sA[i] = expf(s[e] - m) / denom;
        sSrc[i] = src[e];
    }
    __syncthreads();
    // gather-accumulate: tid<128 -> hn[src] cols, tid>=128 -> w2 cols
    float acc = 0.f;
    const bool lo = tid < 128;
    for (int i = 0; i < deg; ++i){
        int e, sI; float a;
        if (i < MAXD){ e = sE[i]; a = sA[i]; sI = sSrc[i]; }
        else { e = eidx[start+i]; a = expf(s[e]-m)/denom; sI = src[e]; }
        float v = lo ? hn[(size_t)sI*128 + tid] : w2[(size_t)e*128 + (tid-128)];
        acc = fmaf(a, v, acc);
    }
    hagg[(size_t)n*256 + tid] = acc;
    if (tid == 0) den[n] = (deg > 0) ? denom : 0.f;
}

// ---------------- k6: h_new = [h_agg, hn] @ W_conc + b_conc ; indeg select ----------------
__global__ __launch_bounds__(TB) void k6_conc(const float* __restrict__ hagg,
                                              const float* __restrict__ hn,
                                              const float* __restrict__ Wc,
                                              const float* __restrict__ bc,
                                              const float* __restrict__ den,
                                              float* __restrict__ hout){
    __shared__ float Ast[BK][ASTR];
    __shared__ float Bs[BK][BN];
    __shared__ float sBc[BN];
    const int tid = threadIdx.x;
    const int rbase = blockIdx.x * BM;
    const int tc = tid & 15, tr = tid >> 4;
    const int r0 = tr*4, c0 = tc*4;
    if (tid < BN) sBc[tid] = bc[tid];
    float acc[4][8] = {};
    for (int chunk = 0; chunk < 12; ++chunk){
        int kc = chunk * BK;
        __syncthreads();
        {
            int lr = tid >> 3, k4 = (tid & 7) << 2;
#pragma unroll
            for (int p = 0; p < 2; ++p){
                int r = p*32 + lr;
                int rr = rbase + r; if (rr >= NN) rr = NN-1;
                float4 v;
                if (chunk < 8) v = *(const float4*)&hagg[(size_t)rr*256 + kc + k4];
                else           v = *(const float4*)&hn[(size_t)rr*128 + (kc-256) + k4];
                store_At(Ast, k4, r, v);
            }
        }
        load_B(Wc, kc, Bs, tid);
        __syncthreads();
        mm_chunk(Ast, Bs, r0, c0, acc);
    }
#pragma unroll
    for (int i = 0; i < 4; ++i){
        int rr = rbase + r0 + i;
        if (rr >= NN) continue;
        bool keep = den[rr] > 0.f;
        float4 h0 = *(const float4*)&hn[(size_t)rr*128 + c0];
        float4 h1 = *(const float4*)&hn[(size_t)rr*128 + 64 + c0];
        float4 o0, o1;
        o0.x = keep ? acc[i][0] + sBc[c0+0] : h0.x;
        o0.y = keep ? acc[i][1] + sBc[c0+1] : h0.y;
        o0.z = keep ? acc[i][2] + sBc[c0+2] : h0.z;
        o0.w = keep ? acc[i][3] + sBc[c0+3] : h0.w;
        o1.x = keep ? acc[i][4] + sBc[64+c0+0] : h1.x;
        o1.y = keep ? acc[i][5] + sBc[64+c0+1] : h1.y;
        o1.z = keep ? acc[i][6] + sBc[64+c0+2] : h1.z;
        o1.w = keep ? acc[i][7] + sBc[64+c0+3] : h1.w;
        *(float4*)&hout[(size_t)rr*128 + c0] = o0;
        *(float4*)&hout[(size_t)rr*128 + 64 + c0] = o1;
    }
}

// ---------------- k7: w_out = [h_out[src], h_out[dst], w_bn, ow] @ W_aggre ----------------
__global__ __launch_bounds__(TB) void k7_out(const float* __restrict__ hout,
                                             const float* __restrict__ ow,
                                             const float* __restrict__ gamma,
                                             const float* __restrict__ beta,
                                             const float* __restrict__ Wa,
                                             const int* __restrict__ src,
                                             const int* __restrict__ dst,
                                             float* __restrict__ w2out){
    __shared__ float Ast[BK][ASTR];
    __shared__ float Bs[BK][BN];
    __shared__ int sSrc[BM], sDst[BM];
    const int tid = threadIdx.x;
    const int rbase = blockIdx.x * BM;
    const int tc = tid & 15, tr = tid >> 4;
    const int r0 = tr*4, c0 = tc*4;
    const float ISR = 0.9999950000374997f;  // 1/sqrt(1+1e-5)
    if (tid < BM){ sSrc[tid] = src[rbase+tid]; sDst[tid] = dst[rbase+tid]; }
    float acc[4][8] = {};
    for (int chunk = 0; chunk < 16; ++chunk){
        int kc = chunk * BK;
        __syncthreads();
        {
            int lr = tid >> 3, k4 = (tid & 7) << 2;
#pragma unroll
            for (int p = 0; p < 2; ++p){
                int r = p*32 + lr;
                int rr = rbase + r;
                float4 v;
                if (chunk < 4){
                    v = *(const float4*)&hout[(size_t)sSrc[r]*128 + kc + k4];
                } else if (chunk < 8){
                    v = *(const float4*)&hout[(size_t)sDst[r]*128 + (kc-128) + k4];
                } else if (chunk < 12){
                    int cb = (kc - 256) + k4;
                    float4 g = *(const float4*)&gamma[cb];
                    float4 b = *(const float4*)&beta[cb];
                    v = *(const float4*)&w2out[(size_t)rr*128 + cb];
                    v.x = v.x*ISR*g.x + b.x;
                    v.y = v.y*ISR*g.y + b.y;
                    v.z = v.z*ISR*g.z + b.z;
                    v.w = v.w*ISR*g.w + b.w;
                } else {
                    v = *(const float4*)&ow[(size_t)rr*128 + (kc-384) + k4];
                }
                store_At(Ast, k4, r, v);
            }
        }
        load_B(Wa, kc, Bs, tid);
        __syncthreads();
        mm_chunk(Ast, Bs, r0, c0, acc);
    }
#pragma unroll
    for (int i = 0; i < 4; ++i){
        int rr = rbase + r0 + i;
        float4 o0 = {acc[i][0],acc[i][1],acc[i][2],acc[i][3]};
        float4 o1 = {acc[i][4],acc[i][5],acc[i][6],acc[i][7]};
        *(float4*)&w2out[(size_t)rr*128 + c0] = o0;
        *(float4*)&w2out[(size_t)rr*128 + 64 + c0] = o1;
    }
}

extern "C" void kernel_launch(void* const* d_in, const int* in_sizes, int n_in,
                              void* d_out, int out_size, void* d_ws, size_t ws_size,
                              hipStream_t stream){
    (void)in_sizes; (void)n_in; (void)out_size;
    const float* h       = (const float*)d_in[0];
    const float* edge_w  = (const float*)d_in[1];
    const float* W_node  = (const float*)d_in[2];
    const float* W_eedge = (const float*)d_in[3];
    const float* W_esf   = (const float*)d_in[4];
    const float* W_fuse  = (const float*)d_in[5];
    const float* b_fuse  = (const float*)d_in[6];
    const float* W_attn  = (const float*)d_in[7];
    const float* W_conc  = (const float*)d_in[8];
    const float* b_conc  = (const float*)d_in[9];
    const float* gamma   = (const float*)d_in[10];
    const float* beta    = (const float*)d_in[11];
    const float* W_aggre = (const float*)d_in[12];
    const int*   src     = (const int*)d_in[13];
    const int*   dst     = (const int*)d_in[14];

    float* out    = (float*)d_out;
    float* o_hout = out + OUT_HOUT;
    float* o_wout = out + OUT_WOUT;   // holds w2 until k7 overwrites with w_out
    float* o_sat  = out + OUT_SAT;

    if (ws_size < (size_t)WS_FLOATS * 4) return;  // fail loudly via validation
    float* ws     = (float*)d_ws;
    float* w_hn   = ws + OFF_HN;
    float* w_ow   = ws + OFF_OW;
    float* w_s    = ws + OFF_S;
    float* w_den  = ws + OFF_DEN;
    int*   w_cur  = (int*)(ws + OFF_CUR);
    float* w_hagg = ws + OFF_HAGG;

    // eidx + offs scratch lives in the h_out output region (overwritten later by k6)
    int* w_eidx = (int*)o_hout;          // E ints
    int* w_offs = w_eidx + NE;           // N ints

    hipLaunchKernelGGL(kA_init,   dim3((NN+TB-1)/TB), dim3(TB), 0, stream, w_cur);
    hipLaunchKernelGGL(kB_count,  dim3(NE/TB), dim3(TB), 0, stream, dst, w_cur);
    hipLaunchKernelGGL(kC_scan,   dim3(1), dim3(TB), 0, stream, w_cur, w_offs);
    hipLaunchKernelGGL(kD_scatter,dim3(NE/TB), dim3(TB), 0, stream, dst, w_cur, w_eidx);
    hipLaunchKernelGGL(k1_hn,     dim3((NN+BM-1)/BM), dim3(TB), 0, stream, h, W_node, w_hn);
    hipLaunchKernelGGL(k2_ow,     dim3(NE/BM), dim3(TB), 0, stream, edge_w, W_eedge, W_esf, w_ow, o_sat);
    hipLaunchKernelGGL(k3_fuse,   dim3(NE/BM), dim3(TB), 0, stream, w_hn, W_fuse, b_fuse, W_attn,
                       src, dst, o_sat, o_wout, w_s);
    hipLaunchKernelGGL(k5_agg,    dim3(NN), dim3(TB), 0, stream, w_s, w_hn, o_wout,
                       src, w_eidx, w_offs, w_cur, w_hagg, w_den);
    hipLaunchKernelGGL(k6_conc,   dim3((NN+BM-1)/BM), dim3(TB), 0, stream, w_hagg, w_hn,
                       W_conc, b_conc, w_den, o_hout);
    hipLaunchKernelGGL(k7_out,    dim3(NE/BM), dim3(TB), 0, stream, o_hout, w_ow, gamma, beta,
                       W_aggre, src, dst, o_wout);
}

// Round 3
// 850.566 us; speedup vs baseline: 2.6710x; 1.6210x over previous
//
#include <hip/hip_runtime.h>
#include <hip/hip_bf16.h>

#define TB 256
#define BM 64
#define BK 32
#define BN 128
#define ASTR 68   // BM + 4 (fp32 path, k1/k6)
#define MAXD 160  // per-node edge cache for k5

static constexpr int NN = 20000;
static constexpr int NE = 320000;

// workspace layout (floats)
static constexpr long long OFF_HN   = 0;          // N*128
static constexpr long long OFF_OW   = 2560000;    // E*128 fp32
static constexpr long long OFF_S    = 43520000;   // E  (raw attention scalar s)
static constexpr long long OFF_DEN  = 43840000;   // N
static constexpr long long OFF_CUR  = 43860000;   // N ints
static constexpr long long OFF_HAGG = 43880000;   // N*256  (ends 49,000,000)
static constexpr long long OFF_WT   = 49000000;   // split-bf16 transposed weights (ushort)
static constexpr long long WS_FLOATS = 49140000;  // ~196.6 MB

// Wt sub-offsets in ushort units from OFF_WT base
static constexpr int U_E = 0;        // W_eedge^T hi [128][128]; lo at +16384
static constexpr int U_F = 32768;    // W_fuse^T  hi [128][384]; lo at +49152
static constexpr int U_A = 131072;   // W_aggre^T hi [128][512]; lo at +65536

// d_out layout (floats): h_out, w_out, sat
static constexpr long long OUT_HOUT = 0;
static constexpr long long OUT_WOUT = 2560000;    // holds w2 until k7 overwrites with w_out
static constexpr long long OUT_SAT  = 43520000;

typedef __attribute__((ext_vector_type(8))) short s8v;      // 8 bf16 (4 VGPR)
typedef __attribute__((ext_vector_type(4))) float f32x4;

#define MFMA16(a,b,c) __builtin_amdgcn_mfma_f32_16x16x32_bf16(a,b,c,0,0,0)

__device__ __forceinline__ float lrelu(float x){ return x >= 0.f ? x : 0.1f*x; }

// ---- split fp32 -> (hi,lo) bf16, RNE both; hi+lo carries ~17 mantissa bits ----
__device__ __forceinline__ void split1(float f, unsigned short& hi, unsigned short& lo){
    __hip_bfloat16 h = __float2bfloat16(f);
    float hf = __bfloat162float(h);
    __hip_bfloat16 l = __float2bfloat16(f - hf);
    hi = __builtin_bit_cast(unsigned short, h);
    lo = __builtin_bit_cast(unsigned short, l);
}
__device__ __forceinline__ void split8(float4 a, float4 b, s8v& hi, s8v& lo){
    float v[8] = {a.x,a.y,a.z,a.w,b.x,b.y,b.z,b.w};
#pragma unroll
    for (int j = 0; j < 8; ++j){
        unsigned short hs, ls;
        split1(v[j], hs, ls);
        hi[j] = (short)hs; lo[j] = (short)ls;
    }
}

// LDS tile addressing: [128 rows][32 k] bf16, 16B-slot XOR swizzle (T2 family)
__device__ __forceinline__ int lds_a(int row, int g){
    return row*32 + ((g ^ (row & 3)) << 3);   // ushort index, 16B aligned
}

// ================= fp32 helpers for k1/k6 (unchanged path) =================
__device__ __forceinline__ void store_At(float (*Ast)[ASTR], int k4, int r, float4 v){
    Ast[k4+0][r] = v.x; Ast[k4+1][r] = v.y; Ast[k4+2][r] = v.z; Ast[k4+3][r] = v.w;
}
__device__ __forceinline__ void mm_chunk(const float (*Ast)[ASTR], const float (*Bs)[BN],
                                         int r0, int c0, float acc[4][8]){
#pragma unroll 4
    for (int k = 0; k < BK; ++k){
        const float4 av = *(const float4*)&Ast[k][r0];
        const float4 b0 = *(const float4*)&Bs[k][c0];
        const float4 b1 = *(const float4*)&Bs[k][64 + c0];
        const float a0=av.x, a1=av.y, a2=av.z, a3=av.w;
        const float b[8] = {b0.x,b0.y,b0.z,b0.w,b1.x,b1.y,b1.z,b1.w};
#pragma unroll
        for (int j = 0; j < 8; ++j){
            acc[0][j] = fmaf(a0, b[j], acc[0][j]);
            acc[1][j] = fmaf(a1, b[j], acc[1][j]);
            acc[2][j] = fmaf(a2, b[j], acc[2][j]);
            acc[3][j] = fmaf(a3, b[j], acc[3][j]);
        }
    }
}
__device__ __forceinline__ void load_B(const float* __restrict__ W, int kc,
                                       float (*Bs)[BN], int tid){
#pragma unroll
    for (int p = 0; p < 4; ++p){
        int idx = p*TB + tid;
        int row = idx >> 5;
        int c4  = (idx & 31) << 2;
        *(float4*)&Bs[row][c4] = *(const float4*)&W[(size_t)(kc+row)*BN + c4];
    }
}

// block-wide reductions (k5)
__device__ __forceinline__ float blockMax(float v, float* sh4){
#pragma unroll
    for (int m = 32; m; m >>= 1) v = fmaxf(v, __shfl_xor(v, m));
    if ((threadIdx.x & 63) == 0) sh4[threadIdx.x >> 6] = v;
    __syncthreads();
    float r = fmaxf(fmaxf(sh4[0], sh4[1]), fmaxf(sh4[2], sh4[3]));
    __syncthreads();
    return r;
}
__device__ __forceinline__ float blockSum(float v, float* sh4){
#pragma unroll
    for (int m = 32; m; m >>= 1) v += __shfl_xor(v, m);
    if ((threadIdx.x & 63) == 0) sh4[threadIdx.x >> 6] = v;
    __syncthreads();
    float r = sh4[0] + sh4[1] + sh4[2] + sh4[3];
    __syncthreads();
    return r;
}

// ---------------- sort pipeline ----------------
__global__ __launch_bounds__(TB) void kA_init(int* __restrict__ cur){
    int i = blockIdx.x*TB + threadIdx.x;
    if (i < NN) cur[i] = 0;
}
__global__ __launch_bounds__(TB) void kB_count(const int* __restrict__ dst,
                                               int* __restrict__ cur){
    int e = blockIdx.x*TB + threadIdx.x;
    atomicAdd(&cur[dst[e]], 1);
}
__global__ __launch_bounds__(TB) void kC_scan(int* __restrict__ cur,
                                              int* __restrict__ offs){
    __shared__ int part[TB];
    __shared__ int spre[TB];
    const int tid = threadIdx.x;
    const int CH = (NN + TB - 1) / TB;
    const int base = tid * CH;
    int sum = 0;
    for (int i = 0; i < CH; ++i){ int idx = base + i; if (idx < NN) sum += cur[idx]; }
    part[tid] = sum;
    __syncthreads();
    if (tid == 0){ int r = 0; for (int i = 0; i < TB; ++i){ spre[i] = r; r += part[i]; } }
    __syncthreads();
    int run = spre[tid];
    for (int i = 0; i < CH; ++i){
        int idx = base + i;
        if (idx < NN){ int c = cur[idx]; offs[idx] = run; cur[idx] = run; run += c; }
    }
}
__global__ __launch_bounds__(TB) void kD_scatter(const int* __restrict__ dst,
                                                 int* __restrict__ cur,
                                                 int* __restrict__ eidx){
    int e = blockIdx.x*TB + threadIdx.x;
    int p = atomicAdd(&cur[dst[e]], 1);
    eidx[p] = e;
}

// ---------------- kW: weight transpose + split (W[K][128] -> Wt[128][K] hi/lo) ----------------
__global__ __launch_bounds__(TB) void kW_prep(const float* __restrict__ W,
                                              unsigned short* __restrict__ wtH,
                                              unsigned short* __restrict__ wtL,
                                              int K){
    int id = blockIdx.x*TB + threadIdx.x;
    if (id >= 128*K) return;
    int n = id / K, k = id - n*K;
    unsigned short hs, ls;
    split1(W[(size_t)k*128 + n], hs, ls);
    wtH[id] = hs; wtL[id] = ls;
}

// ---------------- k1: hn = h @ W_node (fp32 path) ----------------
__global__ __launch_bounds__(TB) void k1_hn(const float* __restrict__ h,
                                            const float* __restrict__ Wn,
                                            float* __restrict__ hn){
    __shared__ float Ast[BK][ASTR];
    __shared__ float Bs[BK][BN];
    const int tid = threadIdx.x;
    const int rbase = blockIdx.x * BM;
    const int tc = tid & 15, tr = tid >> 4;
    const int r0 = tr*4, c0 = tc*4;
    float acc[4][8] = {};
    for (int kc = 0; kc < 128; kc += BK){
        __syncthreads();
        {
            int lr = tid >> 3, k4 = (tid & 7) << 2;
#pragma unroll
            for (int p = 0; p < 2; ++p){
                int r = p*32 + lr;
                int rr = rbase + r; if (rr >= NN) rr = NN-1;
                float4 v = *(const float4*)&h[(size_t)rr*128 + kc + k4];
                store_At(Ast, k4, r, v);
            }
        }
        load_B(Wn, kc, Bs, tid);
        __syncthreads();
        mm_chunk(Ast, Bs, r0, c0, acc);
    }
#pragma unroll
    for (int i = 0; i < 4; ++i){
        int rr = rbase + r0 + i;
        if (rr < NN){
            float4 o0 = {acc[i][0],acc[i][1],acc[i][2],acc[i][3]};
            float4 o1 = {acc[i][4],acc[i][5],acc[i][6],acc[i][7]};
            *(float4*)&hn[(size_t)rr*128 + c0] = o0;
            *(float4*)&hn[(size_t)rr*128 + 64 + c0] = o1;
        }
    }
}

// ================== MFMA split-bf16 edge GEMMs ==================
// block = 256 thr (4 waves), tile 128 rows x 128 cols, BK=32
// wave w: rows w*32..w*32+31 (2 row-tiles); acc[rt][ct] f32x4

// ---------------- k2: ow = edge_w @ W_eedge ; w1 = (lrelu(ow)@W_esf)*ow ----------------
__global__ __launch_bounds__(TB) void k2_mfma(const float* __restrict__ ew,
                                              const unsigned short* __restrict__ wtH,
                                              const unsigned short* __restrict__ wtL,
                                              const float* __restrict__ Wesf,
                                              float* __restrict__ ow,
                                              float* __restrict__ sat){
    __shared__ __align__(16) unsigned short Ah[4096], Al[4096], Bh[4096], Bl[4096];
    __shared__ float sEsf[128];
    const int tid = threadIdx.x;
    const long long rbase = (long long)blockIdx.x * 128;
    const int lane = tid & 63, w = tid >> 6;
    const int ls = lane & 15, lg = lane >> 4;
    if (tid < 128) sEsf[tid] = Wesf[tid];
    f32x4 acc[2][8] = {};
    for (int kc = 0; kc < 128; kc += 32){
        __syncthreads();
#pragma unroll
        for (int u = 0; u < 2; ++u){
            int id = tid + u*256;
            int row = id >> 2, g = id & 3;
            int kk = kc + g*8;
            const float* p = &ew[(rbase + row)*128 + kk];
            float4 v0 = *(const float4*)p, v1 = *(const float4*)(p+4);
            s8v hi, lo; split8(v0, v1, hi, lo);
            *(s8v*)&Ah[lds_a(row,g)] = hi; *(s8v*)&Al[lds_a(row,g)] = lo;
            int col = row;  // same decomposition for B tile
            *(s8v*)&Bh[lds_a(col,g)] = *(const s8v*)&wtH[col*128 + kk];
            *(s8v*)&Bl[lds_a(col,g)] = *(const s8v*)&wtL[col*128 + kk];
        }
        __syncthreads();
        s8v ah[2], al[2];
#pragma unroll
        for (int rt = 0; rt < 2; ++rt){
            int r = w*32 + rt*16 + ls;
            ah[rt] = *(const s8v*)&Ah[lds_a(r,lg)];
            al[rt] = *(const s8v*)&Al[lds_a(r,lg)];
        }
#pragma unroll
        for (int ct = 0; ct < 8; ++ct){
            int c = ct*16 + ls;
            s8v bh = *(const s8v*)&Bh[lds_a(c,lg)];
            s8v bl = *(const s8v*)&Bl[lds_a(c,lg)];
#pragma unroll
            for (int rt = 0; rt < 2; ++rt){
                acc[rt][ct] = MFMA16(ah[rt], bh, acc[rt][ct]);
                acc[rt][ct] = MFMA16(ah[rt], bl, acc[rt][ct]);
                acc[rt][ct] = MFMA16(al[rt], bh, acc[rt][ct]);
            }
        }
    }
    // epilogue
#pragma unroll
    for (int rt = 0; rt < 2; ++rt){
#pragma unroll
        for (int reg = 0; reg < 4; ++reg){
            float p = 0.f;
#pragma unroll
            for (int ct = 0; ct < 8; ++ct)
                p += lrelu(acc[rt][ct][reg]) * sEsf[ct*16 + ls];
#pragma unroll
            for (int m = 1; m < 16; m <<= 1) p += __shfl_xor(p, m);
            long long orow = rbase + w*32 + rt*16 + lg*4 + reg;
#pragma unroll
            for (int ct = 0; ct < 8; ++ct){
                float o = acc[rt][ct][reg];
                int col = ct*16 + ls;
                ow[orow*128 + col] = o;
                sat[orow*384 + 256 + col] = p * o;
            }
        }
    }
}

// ---------------- k3: sat build + inw GEMM + attn dot + w2 + s ----------------
__global__ __launch_bounds__(TB) void k3_mfma(const float* __restrict__ hn,
                                              const unsigned short* __restrict__ wtH,
                                              const unsigned short* __restrict__ wtL,
                                              const float* __restrict__ bf,
                                              const float* __restrict__ Wattn,
                                              const int* __restrict__ src,
                                              const int* __restrict__ dst,
                                              float* __restrict__ sat,
                                              float* __restrict__ w2,
                                              float* __restrict__ s_ws){
    __shared__ __align__(16) unsigned short Ah[4096], Al[4096], Bh[4096], Bl[4096];
    __shared__ float sBf[128], sAtt[128];
    __shared__ int sSrc[128], sDst[128];
    const int tid = threadIdx.x;
    const long long rbase = (long long)blockIdx.x * 128;
    const int lane = tid & 63, w = tid >> 6;
    const int ls = lane & 15, lg = lane >> 4;
    if (tid < 128){
        sBf[tid] = bf[tid]; sAtt[tid] = Wattn[tid];
        sSrc[tid] = src[rbase + tid]; sDst[tid] = dst[rbase + tid];
    }
    f32x4 acc[2][8] = {};
    for (int kc = 0; kc < 384; kc += 32){
        __syncthreads();
#pragma unroll
        for (int u = 0; u < 2; ++u){
            int id = tid + u*256;
            int row = id >> 2, g = id & 3;
            int kk = kc + g*8;
            long long e = rbase + row;
            float4 v0, v1;
            if (kk < 128){
                const float* p = &hn[(size_t)sSrc[row]*128 + kk];
                v0 = *(const float4*)p; v1 = *(const float4*)(p+4);
                *(float4*)&sat[e*384 + kk] = v0; *(float4*)&sat[e*384 + kk + 4] = v1;
            } else if (kk < 256){
                const float* p = &hn[(size_t)sDst[row]*128 + (kk-128)];
                v0 = *(const float4*)p; v1 = *(const float4*)(p+4);
                *(float4*)&sat[e*384 + kk] = v0; *(float4*)&sat[e*384 + kk + 4] = v1;
            } else {
                const float* p = &sat[e*384 + kk];   // w1 written by k2
                v0 = *(const float4*)p; v1 = *(const float4*)(p+4);
            }
            s8v hi, lo; split8(v0, v1, hi, lo);
            *(s8v*)&Ah[lds_a(row,g)] = hi; *(s8v*)&Al[lds_a(row,g)] = lo;
            int col = row;
            *(s8v*)&Bh[lds_a(col,g)] = *(const s8v*)&wtH[col*384 + kk];
            *(s8v*)&Bl[lds_a(col,g)] = *(const s8v*)&wtL[col*384 + kk];
        }
        __syncthreads();
        s8v ah[2], al[2];
#pragma unroll
        for (int rt = 0; rt < 2; ++rt){
            int r = w*32 + rt*16 + ls;
            ah[rt] = *(const s8v*)&Ah[lds_a(r,lg)];
            al[rt] = *(const s8v*)&Al[lds_a(r,lg)];
        }
#pragma unroll
        for (int ct = 0; ct < 8; ++ct){
            int c = ct*16 + ls;
            s8v bh = *(const s8v*)&Bh[lds_a(c,lg)];
            s8v bl = *(const s8v*)&Bl[lds_a(c,lg)];
#pragma unroll
            for (int rt = 0; rt < 2; ++rt){
                acc[rt][ct] = MFMA16(ah[rt], bh, acc[rt][ct]);
                acc[rt][ct] = MFMA16(ah[rt], bl, acc[rt][ct]);
                acc[rt][ct] = MFMA16(al[rt], bh, acc[rt][ct]);
            }
        }
    }
    // epilogue: attn dot -> s; w2 = s * w1
#pragma unroll
    for (int rt = 0; rt < 2; ++rt){
#pragma unroll
        for (int reg = 0; reg < 4; ++reg){
            float p = 0.f;
#pragma unroll
            for (int ct = 0; ct < 8; ++ct){
                int col = ct*16 + ls;
                p += lrelu(acc[rt][ct][reg] + sBf[col]) * sAtt[col];
            }
#pragma unroll
            for (int m = 1; m < 16; m <<= 1) p += __shfl_xor(p, m);
            long long orow = rbase + w*32 + rt*16 + lg*4 + reg;
            if (ls == 0) s_ws[orow] = p;
#pragma unroll
            for (int ct = 0; ct < 8; ++ct){
                int col = ct*16 + ls;
                float w1 = sat[orow*384 + 256 + col];   // L2-hot (just staged)
                w2[orow*128 + col] = p * w1;
            }
        }
    }
}

// ---------------- k5: per-node softmax + gather-aggregate ----------------
__global__ __launch_bounds__(TB) void k5_agg(const float* __restrict__ s,
                                             const float* __restrict__ hn,
                                             const float* __restrict__ w2,
                                             const int* __restrict__ src,
                                             const int* __restrict__ eidx,
                                             const int* __restrict__ offs,
                                             const int* __restrict__ cur,
                                             float* __restrict__ hagg,
                                             float* __restrict__ den){
    __shared__ int   sE[MAXD];
    __shared__ int   sSrc[MAXD];
    __shared__ float sA[MAXD];
    __shared__ float sh4[4];
    const int n = blockIdx.x, tid = threadIdx.x;
    const int start = offs[n];
    const int deg = cur[n] - start;
    for (int i = tid; i < deg && i < MAXD; i += TB) sE[i] = eidx[start+i];
    __syncthreads();
    if (tid == 0 && deg > 1){
        int dd = deg < MAXD ? deg : MAXD;
        for (int i = 1; i < dd; ++i){
            int key = sE[i], j = i-1;
            while (j >= 0 && sE[j] > key){ sE[j+1] = sE[j]; --j; }
            sE[j+1] = key;
        }
    }
    __syncthreads();
    float lm = -3.402823466e38f;
    for (int i = tid; i < deg; i += TB){
        int e = (i < MAXD) ? sE[i] : eidx[start+i];
        lm = fmaxf(lm, s[e]);
    }
    const float m = blockMax(lm, sh4);
    float lsum = 0.f;
    for (int i = tid; i < deg; i += TB){
        int e = (i < MAXD) ? sE[i] : eidx[start+i];
        lsum += expf(s[e] - m);
    }
    const float denom = blockSum(lsum, sh4);
    for (int i = tid; i < deg && i < MAXD; i += TB){
        int e = sE[i];
        sA[i] = expf(s[e] - m) / denom;
        sSrc[i] = src[e];
    }
    __syncthreads();
    float acc = 0.f;
    const bool lo = tid < 128;
    for (int i = 0; i < deg; ++i){
        int e, sI; float a;
        if (i < MAXD){ e = sE[i]; a = sA[i]; sI = sSrc[i]; }
        else { e = eidx[start+i]; a = expf(s[e]-m)/denom; sI = src[e]; }
        float v = lo ? hn[(size_t)sI*128 + tid] : w2[(size_t)e*128 + (tid-128)];
        acc = fmaf(a, v, acc);
    }
    hagg[(size_t)n*256 + tid] = acc;
    if (tid == 0) den[n] = (deg > 0) ? denom : 0.f;
}

// ---------------- k6: h_new = [h_agg, hn] @ W_conc + b_conc ; indeg select ----------------
__global__ __launch_bounds__(TB) void k6_conc(const float* __restrict__ hagg,
                                              const float* __restrict__ hn,
                                              const float* __restrict__ Wc,
                                              const float* __restrict__ bc,
                                              const float* __restrict__ den,
                                              float* __restrict__ hout){
    __shared__ float Ast[BK][ASTR];
    __shared__ float Bs[BK][BN];
    __shared__ float sBc[BN];
    const int tid = threadIdx.x;
    const int rbase = blockIdx.x * BM;
    const int tc = tid & 15, tr = tid >> 4;
    const int r0 = tr*4, c0 = tc*4;
    if (tid < BN) sBc[tid] = bc[tid];
    float acc[4][8] = {};
    for (int chunk = 0; chunk < 12; ++chunk){
        int kc = chunk * BK;
        __syncthreads();
        {
            int lr = tid >> 3, k4 = (tid & 7) << 2;
#pragma unroll
            for (int p = 0; p < 2; ++p){
                int r = p*32 + lr;
                int rr = rbase + r; if (rr >= NN) rr = NN-1;
                float4 v;
                if (chunk < 8) v = *(const float4*)&hagg[(size_t)rr*256 + kc + k4];
                else           v = *(const float4*)&hn[(size_t)rr*128 + (kc-256) + k4];
                store_At(Ast, k4, r, v);
            }
        }
        load_B(Wc, kc, Bs, tid);
        __syncthreads();
        mm_chunk(Ast, Bs, r0, c0, acc);
    }
#pragma unroll
    for (int i = 0; i < 4; ++i){
        int rr = rbase + r0 + i;
        if (rr >= NN) continue;
        bool keep = den[rr] > 0.f;
        float4 h0 = *(const float4*)&hn[(size_t)rr*128 + c0];
        float4 h1 = *(const float4*)&hn[(size_t)rr*128 + 64 + c0];
        float4 o0, o1;
        o0.x = keep ? acc[i][0] + sBc[c0+0] : h0.x;
        o0.y = keep ? acc[i][1] + sBc[c0+1] : h0.y;
        o0.z = keep ? acc[i][2] + sBc[c0+2] : h0.z;
        o0.w = keep ? acc[i][3] + sBc[c0+3] : h0.w;
        o1.x = keep ? acc[i][4] + sBc[64+c0+0] : h1.x;
        o1.y = keep ? acc[i][5] + sBc[64+c0+1] : h1.y;
        o1.z = keep ? acc[i][6] + sBc[64+c0+2] : h1.z;
        o1.w = keep ? acc[i][7] + sBc[64+c0+3] : h1.w;
        *(float4*)&hout[(size_t)rr*128 + c0] = o0;
        *(float4*)&hout[(size_t)rr*128 + 64 + c0] = o1;
    }
}

// ---------------- k7: w_out = [h_out[src], h_out[dst], w_bn, ow] @ W_aggre ----------------
__global__ __launch_bounds__(TB) void k7_mfma(const float* __restrict__ hout,
                                              const float* __restrict__ ow,
                                              const float* __restrict__ gamma,
                                              const float* __restrict__ beta,
                                              const unsigned short* __restrict__ wtH,
                                              const unsigned short* __restrict__ wtL,
                                              const int* __restrict__ src,
                                              const int* __restrict__ dst,
                                              float* __restrict__ w2out){
    __shared__ __align__(16) unsigned short Ah[4096], Al[4096], Bh[4096], Bl[4096];
    __shared__ float sGam[128], sBet[128];
    __shared__ int sSrc[128], sDst[128];
    const int tid = threadIdx.x;
    const long long rbase = (long long)blockIdx.x * 128;
    const int lane = tid & 63, w = tid >> 6;
    const int ls = lane & 15, lg = lane >> 4;
    const float ISR = 0.9999950000374997f;  // 1/sqrt(1+1e-5)
    if (tid < 128){
        sGam[tid] = gamma[tid] * ISR; sBet[tid] = beta[tid];
        sSrc[tid] = src[rbase + tid]; sDst[tid] = dst[rbase + tid];
    }
    f32x4 acc[2][8] = {};
    for (int kc = 0; kc < 512; kc += 32){
        __syncthreads();
#pragma unroll
        for (int u = 0; u < 2; ++u){
            int id = tid + u*256;
            int row = id >> 2, g = id & 3;
            int kk = kc + g*8;
            long long e = rbase + row;
            float4 v0, v1;
            if (kk < 128){
                const float* p = &hout[(size_t)sSrc[row]*128 + kk];
                v0 = *(const float4*)p; v1 = *(const float4*)(p+4);
            } else if (kk < 256){
                const float* p = &hout[(size_t)sDst[row]*128 + (kk-128)];
                v0 = *(const float4*)p; v1 = *(const float4*)(p+4);
            } else if (kk < 384){
                int cb = kk - 256;
                const float* p = &w2out[e*128 + cb];
                v0 = *(const float4*)p; v1 = *(const float4*)(p+4);
                v0.x = fmaf(v0.x, sGam[cb+0], sBet[cb+0]);
                v0.y = fmaf(v0.y, sGam[cb+1], sBet[cb+1]);
                v0.z = fmaf(v0.z, sGam[cb+2], sBet[cb+2]);
                v0.w = fmaf(v0.w, sGam[cb+3], sBet[cb+3]);
                v1.x = fmaf(v1.x, sGam[cb+4], sBet[cb+4]);
                v1.y = fmaf(v1.y, sGam[cb+5], sBet[cb+5]);
                v1.z = fmaf(v1.z, sGam[cb+6], sBet[cb+6]);
                v1.w = fmaf(v1.w, sGam[cb+7], sBet[cb+7]);
            } else {
                const float* p = &ow[e*128 + (kk-384)];
                v0 = *(const float4*)p; v1 = *(const float4*)(p+4);
            }
            s8v hi, lo; split8(v0, v1, hi, lo);
            *(s8v*)&Ah[lds_a(row,g)] = hi; *(s8v*)&Al[lds_a(row,g)] = lo;
            int col = row;
            *(s8v*)&Bh[lds_a(col,g)] = *(const s8v*)&wtH[col*512 + kk];
            *(s8v*)&Bl[lds_a(col,g)] = *(const s8v*)&wtL[col*512 + kk];
        }
        __syncthreads();
        s8v ah[2], al[2];
#pragma unroll
        for (int rt = 0; rt < 2; ++rt){
            int r = w*32 + rt*16 + ls;
            ah[rt] = *(const s8v*)&Ah[lds_a(r,lg)];
            al[rt] = *(const s8v*)&Al[lds_a(r,lg)];
        }
#pragma unroll
        for (int ct = 0; ct < 8; ++ct){
            int c = ct*16 + ls;
            s8v bh = *(const s8v*)&Bh[lds_a(c,lg)];
            s8v bl = *(const s8v*)&Bl[lds_a(c,lg)];
#pragma unroll
            for (int rt = 0; rt < 2; ++rt){
                acc[rt][ct] = MFMA16(ah[rt], bh, acc[rt][ct]);
                acc[rt][ct] = MFMA16(ah[rt], bl, acc[rt][ct]);
                acc[rt][ct] = MFMA16(al[rt], bh, acc[rt][ct]);
            }
        }
    }
    // epilogue: plain store (overwrites w2 with w_out; own rows only)
#pragma unroll
    for (int rt = 0; rt < 2; ++rt){
#pragma unroll
        for (int reg = 0; reg < 4; ++reg){
            long long orow = rbase + w*32 + rt*16 + lg*4 + reg;
#pragma unroll
            for (int ct = 0; ct < 8; ++ct)
                w2out[orow*128 + ct*16 + ls] = acc[rt][ct][reg];
        }
    }
}

extern "C" void kernel_launch(void* const* d_in, const int* in_sizes, int n_in,
                              void* d_out, int out_size, void* d_ws, size_t ws_size,
                              hipStream_t stream){
    (void)in_sizes; (void)n_in; (void)out_size;
    const float* h       = (const float*)d_in[0];
    const float* edge_w  = (const float*)d_in[1];
    const float* W_node  = (const float*)d_in[2];
    const float* W_eedge = (const float*)d_in[3];
    const float* W_esf   = (const float*)d_in[4];
    const float* W_fuse  = (const float*)d_in[5];
    const float* b_fuse  = (const float*)d_in[6];
    const float* W_attn  = (const float*)d_in[7];
    const float* W_conc  = (const float*)d_in[8];
    const float* b_conc  = (const float*)d_in[9];
    const float* gamma   = (const float*)d_in[10];
    const float* beta    = (const float*)d_in[11];
    const float* W_aggre = (const float*)d_in[12];
    const int*   src     = (const int*)d_in[13];
    const int*   dst     = (const int*)d_in[14];

    float* out    = (float*)d_out;
    float* o_hout = out + OUT_HOUT;
    float* o_wout = out + OUT_WOUT;
    float* o_sat  = out + OUT_SAT;

    if (ws_size < (size_t)WS_FLOATS * 4) return;
    float* ws     = (float*)d_ws;
    float* w_hn   = ws + OFF_HN;
    float* w_ow   = ws + OFF_OW;
    float* w_s    = ws + OFF_S;
    float* w_den  = ws + OFF_DEN;
    int*   w_cur  = (int*)(ws + OFF_CUR);
    float* w_hagg = ws + OFF_HAGG;
    unsigned short* w_wt = (unsigned short*)(ws + OFF_WT);

    int* w_eidx = (int*)o_hout;          // E ints (pre-k6 scratch)
    int* w_offs = w_eidx + NE;           // N ints

    hipLaunchKernelGGL(kA_init,   dim3((NN+TB-1)/TB), dim3(TB), 0, stream, w_cur);
    hipLaunchKernelGGL(kB_count,  dim3(NE/TB), dim3(TB), 0, stream, dst, w_cur);
    hipLaunchKernelGGL(kC_scan,   dim3(1), dim3(TB), 0, stream, w_cur, w_offs);
    hipLaunchKernelGGL(kD_scatter,dim3(NE/TB), dim3(TB), 0, stream, dst, w_cur, w_eidx);

    hipLaunchKernelGGL(kW_prep, dim3((128*128+TB-1)/TB), dim3(TB), 0, stream,
                       W_eedge, w_wt + U_E, w_wt + U_E + 128*128, 128);
    hipLaunchKernelGGL(kW_prep, dim3((128*384+TB-1)/TB), dim3(TB), 0, stream,
                       W_fuse,  w_wt + U_F, w_wt + U_F + 128*384, 384);
    hipLaunchKernelGGL(kW_prep, dim3((128*512+TB-1)/TB), dim3(TB), 0, stream,
                       W_aggre, w_wt + U_A, w_wt + U_A + 128*512, 512);

    hipLaunchKernelGGL(k1_hn,   dim3((NN+BM-1)/BM), dim3(TB), 0, stream, h, W_node, w_hn);
    hipLaunchKernelGGL(k2_mfma, dim3(NE/128), dim3(TB), 0, stream, edge_w,
                       w_wt + U_E, w_wt + U_E + 128*128, W_esf, w_ow, o_sat);
    hipLaunchKernelGGL(k3_mfma, dim3(NE/128), dim3(TB), 0, stream, w_hn,
                       w_wt + U_F, w_wt + U_F + 128*384, b_fuse, W_attn,
                       src, dst, o_sat, o_wout, w_s);
    hipLaunchKernelGGL(k5_agg,  dim3(NN), dim3(TB), 0, stream, w_s, w_hn, o_wout,
                       src, w_eidx, w_offs, w_cur, w_hagg, w_den);
    hipLaunchKernelGGL(k6_conc, dim3((NN+BM-1)/BM), dim3(TB), 0, stream, w_hagg, w_hn,
                       W_conc, b_conc, w_den, o_hout);
    hipLaunchKernelGGL(k7_mfma, dim3(NE/128), dim3(TB), 0, stream, o_hout, w_ow,
                       gamma, beta, w_wt + U_A, w_wt + U_A + 128*512,
                       src, dst, o_wout);
}